// Round 6
// baseline (203.868 us; speedup 1.0000x reference)
//
#include <hip/hip_runtime.h>

#define N_NODES 50000
#define N_EDGES 800000
#define D 128
#define NBUK 196        // ceil(50000/256) buckets of 256 nodes
#define PCHUNK 3200     // edges per partition block
#define PBLOCKS 250     // 250*3200 = 800000

typedef __bf16 bf16x8 __attribute__((ext_vector_type(8)));
typedef __bf16 bf16x4 __attribute__((ext_vector_type(4)));
typedef float  f32x4  __attribute__((ext_vector_type(4)));

// ws layout (bytes):
//   offsets  @ 0          [50001 i32] -> 200,004 (pad 200,192)
//   btotal   @ 200,192    [256 i32]
//   gcursor  @ 201,216    [256 i32]
//   bbase    @ 202,240    [260 i32]  (pad to 203,776)
//   csr_src  @ 203,776    [800000 i32] -> 3,403,776
//   packed   @ 3,403,776  [800000 i32] -> 6,603,776
//   feat16   @ 3,403,776  [6,400,000 bf16] OVERLAYS packed (packed dead after
//                          csr_local; convert_feat runs after) -> 16,203,776
//   Wc16     @ 16,203,776 [128*256 bf16 = 65,536 B]
//   biasc    @ 16,269,312 [512 B]   total 16,269,824  (<= proven 16,667,136)
#define OFF_OFFSETS   0ull
#define OFF_BTOTAL    200192ull
#define OFF_GCURSOR   201216ull
#define OFF_BBASE     202240ull
#define OFF_CSR       203776ull
#define OFF_PACKED    3403776ull
#define OFF_FEAT16    3403776ull
#define OFF_WC16      16203776ull
#define OFF_BIASC     16269312ull

// ---- CSR build (unchanged from round 5) ------------------------------------

__global__ __launch_bounds__(256)
void bucket_hist_kernel(const int* __restrict__ dst, int* __restrict__ btotal, int n) {
    __shared__ int lh[NBUK];
    const int tid = threadIdx.x;
    for (int i = tid; i < NBUK; i += 256) lh[i] = 0;
    __syncthreads();
    const int e0 = blockIdx.x * PCHUNK;
    const int e1 = min(e0 + PCHUNK, n);
    for (int i = e0 + tid; i < e1; i += 256)
        atomicAdd(&lh[dst[i] >> 8], 1);
    __syncthreads();
    for (int i = tid; i < NBUK; i += 256)
        if (lh[i]) atomicAdd(&btotal[i], lh[i]);
}

__global__ __launch_bounds__(64)
void bucket_scan_kernel(const int* __restrict__ btotal, int* __restrict__ bbase,
                        int* __restrict__ gcursor, int* __restrict__ offsets) {
    const int lane = threadIdx.x;
    int c[4];
    int s = 0;
    #pragma unroll
    for (int j = 0; j < 4; ++j) {
        int idx = lane * 4 + j;
        c[j] = (idx < NBUK) ? btotal[idx] : 0;
        s += c[j];
    }
    int v = s;
    #pragma unroll
    for (int o = 1; o < 64; o <<= 1) {
        int u = __shfl_up(v, o);
        if (lane >= o) v += u;
    }
    int run = v - s;
    #pragma unroll
    for (int j = 0; j < 4; ++j) {
        int idx = lane * 4 + j;
        if (idx < NBUK) { bbase[idx] = run; gcursor[idx] = run; }
        run += c[j];
    }
    if (lane == 63) {
        bbase[NBUK] = v;
        offsets[N_NODES] = v;
    }
}

__global__ __launch_bounds__(256)
void partition_kernel(const int* __restrict__ src, const int* __restrict__ dst,
                      int* __restrict__ gcursor, int* __restrict__ packed, int n) {
    __shared__ int lh[NBUK];
    __shared__ int lbase[NBUK];
    const int tid = threadIdx.x;
    const int e0 = blockIdx.x * PCHUNK;
    const int e1 = min(e0 + PCHUNK, n);
    for (int i = tid; i < NBUK; i += 256) lh[i] = 0;
    __syncthreads();
    for (int i = e0 + tid; i < e1; i += 256)
        atomicAdd(&lh[dst[i] >> 8], 1);
    __syncthreads();
    for (int i = tid; i < NBUK; i += 256) {
        int cnt = lh[i];
        lbase[i] = cnt ? atomicAdd(&gcursor[i], cnt) : 0;
    }
    __syncthreads();
    for (int i = tid; i < NBUK; i += 256) lh[i] = 0;
    __syncthreads();
    for (int i = e0 + tid; i < e1; i += 256) {
        int d = dst[i], s = src[i];
        int b = d >> 8;
        int r = atomicAdd(&lh[b], 1);
        packed[lbase[b] + r] = ((d & 255) << 16) | s;
    }
}

__global__ __launch_bounds__(256)
void csr_local_kernel(const int* __restrict__ packed, const int* __restrict__ bbase,
                      int* __restrict__ offsets, int* __restrict__ csr_src) {
    __shared__ int lh[256];
    __shared__ int loff[256];
    __shared__ int ws4[4];
    const int tid = threadIdx.x;
    const int lane = tid & 63;
    const int wv = tid >> 6;
    const int b = blockIdx.x;
    const int node0 = b * 256;
    const int ncnt = min(256, N_NODES - node0);
    const int lo = bbase[b], hi = bbase[b + 1];

    lh[tid] = 0;
    __syncthreads();
    for (int i = lo + tid; i < hi; i += 256)
        atomicAdd(&lh[packed[i] >> 16], 1);
    __syncthreads();
    int c = lh[tid];
    int v = c;
    #pragma unroll
    for (int o = 1; o < 64; o <<= 1) {
        int u = __shfl_up(v, o);
        if (lane >= o) v += u;
    }
    if (lane == 63) ws4[wv] = v;
    __syncthreads();
    if (tid == 0) {
        int r = 0;
        #pragma unroll
        for (int j = 0; j < 4; ++j) { int t = ws4[j]; ws4[j] = r; r += t; }
    }
    __syncthreads();
    int ex = ws4[wv] + (v - c);
    loff[tid] = ex;
    if (tid < ncnt) offsets[node0 + tid] = lo + ex;
    lh[tid] = 0;
    __syncthreads();
    for (int i = lo + tid; i < hi; i += 256) {
        int p = packed[i];
        int l = p >> 16;
        int r = atomicAdd(&lh[l], 1);
        csr_src[lo + loff[l] + r] = p & 0xFFFF;
    }
}

// ---- conversions -----------------------------------------------------------

// feat (fp32) -> feat16 (bf16). 6.4M elems; thread converts 8.
__global__ __launch_bounds__(256)
void convert_feat_kernel(const float* __restrict__ feat, __bf16* __restrict__ feat16) {
    size_t i = ((size_t)blockIdx.x * 256 + threadIdx.x) * 8;
    if (i >= (size_t)N_NODES * D) return;
    float4 f0 = *(const float4*)(feat + i);
    float4 f1 = *(const float4*)(feat + i + 4);
    bf16x8 t;
    t[0]=(__bf16)f0.x; t[1]=(__bf16)f0.y; t[2]=(__bf16)f0.z; t[3]=(__bf16)f0.w;
    t[4]=(__bf16)f1.x; t[5]=(__bf16)f1.y; t[6]=(__bf16)f1.z; t[7]=(__bf16)f1.w;
    *(bf16x8*)(feat16 + i) = t;
}

// Wc16[col][k]: k<128 -> W_self[col][k], k>=128 -> W_neigh[col][k-128].
// blocks 0..31: weights (thread -> 4 k's); block 32: combined bias.
__global__ __launch_bounds__(256)
void convert_w_kernel(const float* __restrict__ Ws, const float* __restrict__ Wn,
                      const float* __restrict__ b_self, const float* __restrict__ bias,
                      __bf16* __restrict__ Wc16, float* __restrict__ biasc) {
    if (blockIdx.x < 32) {
        int idx = blockIdx.x * 256 + threadIdx.x;   // 8192 quads
        int col = idx >> 6;                          // 64 quads per col (256 k / 4)
        int kq  = (idx & 63) * 4;                    // k base
        const float* srcp = (kq < D) ? (Ws + (size_t)col * D + kq)
                                     : (Wn + (size_t)col * D + (kq - D));
        float4 f = *(const float4*)srcp;
        bf16x4 t;
        t[0]=(__bf16)f.x; t[1]=(__bf16)f.y; t[2]=(__bf16)f.z; t[3]=(__bf16)f.w;
        *(bf16x4*)(Wc16 + (size_t)col * 256 + kq) = t;
    } else if (threadIdx.x < D) {
        biasc[threadIdx.x] = b_self[threadIdx.x] + bias[threadIdx.x];
    }
}

// ---- fused gather-mean + K=256 GEMM ---------------------------------------
// Block: 256 threads, 64-node tile.
// LDS At[64][264] bf16 (row = node): cols 0..127 = feat16 row, 128..255 =
// mean-neighbor row (bf16), 256..263 pad (row stride 528B -> ds_read_b128
// across 16 rows is a free 2-way conflict). Epilogue reuses the same 33,792B
// as Ct[64][132] f32 for a coalesced transpose-store.
__device__ __forceinline__ float bf2f(unsigned short u) {
    union { unsigned int i; float f; } c;
    c.i = (unsigned int)u << 16;
    return c.f;
}

__global__ __launch_bounds__(256)
void fused_kernel(const __bf16* __restrict__ feat16,
                  const int* __restrict__ offsets,
                  const int* __restrict__ csr_src,
                  const __bf16* __restrict__ Wc16,
                  const float* __restrict__ biasc,
                  float* __restrict__ out) {
    __shared__ __bf16 At[64][264];
    const int tid = threadIdx.x;
    const int node0 = blockIdx.x * 64;

    // Phase 1: stage feat16 rows (64 x 128 bf16), 16B per thread-chunk.
    for (int idx = tid; idx < 1024; idx += 256) {
        int row = idx >> 4;
        int seg = (idx & 15) * 8;
        int n = node0 + row;
        bf16x8 v = {};
        if (n < N_NODES) v = *(const bf16x8*)(feat16 + (size_t)n * D + seg);
        *(bf16x8*)&At[row][seg] = v;
    }

    // Phase 2: gather-mean into cols 128..255. Half-wave per node.
    {
        const int hw = tid >> 5;         // 0..7
        const int lane = tid & 31;
        const unsigned short* g = (const unsigned short*)feat16;
        for (int i = hw; i < 64; i += 8) {
            int n = node0 + i;
            float a0 = 0.f, a1 = 0.f, a2 = 0.f, a3 = 0.f;
            int dg = 0;
            if (n < N_NODES) {
                int beg = offsets[n], end = offsets[n + 1];
                dg = end - beg;
                int j = beg;
                for (; j + 1 < end; j += 2) {
                    int s0 = csr_src[j], s1 = csr_src[j + 1];
                    ushort4 u0 = *(const ushort4*)(g + (size_t)s0 * D + lane * 4);
                    ushort4 u1 = *(const ushort4*)(g + (size_t)s1 * D + lane * 4);
                    a0 += bf2f(u0.x) + bf2f(u1.x);
                    a1 += bf2f(u0.y) + bf2f(u1.y);
                    a2 += bf2f(u0.z) + bf2f(u1.z);
                    a3 += bf2f(u0.w) + bf2f(u1.w);
                }
                if (j < end) {
                    ushort4 u0 = *(const ushort4*)(g + (size_t)csr_src[j] * D + lane * 4);
                    a0 += bf2f(u0.x); a1 += bf2f(u0.y);
                    a2 += bf2f(u0.z); a3 += bf2f(u0.w);
                }
            }
            float sc = dg > 0 ? 1.0f / (float)dg : 0.f;   // DGL mean: deg==0 -> 0
            bf16x4 hv;
            hv[0] = (__bf16)(a0 * sc); hv[1] = (__bf16)(a1 * sc);
            hv[2] = (__bf16)(a2 * sc); hv[3] = (__bf16)(a3 * sc);
            *(bf16x4*)&At[i][128 + lane * 4] = hv;
        }
    }
    __syncthreads();

    // Phase 3: K=256 MFMA GEMM. Wave w: rows (w&1)*32..+32, cols (w>>1)*64..+64.
    const int wv = tid >> 6;
    const int lane = tid & 63;
    const int m = lane & 15;
    const int quad = lane >> 4;
    const int r0 = (wv & 1) * 32;
    const int c0 = (wv >> 1) * 64;

    f32x4 acc[2][4] = {};
    #pragma unroll
    for (int k0 = 0; k0 < 256; k0 += 32) {
        const int kk = k0 + quad * 8;
        bf16x8 a0 = *(const bf16x8*)&At[r0 + m][kk];
        bf16x8 a1 = *(const bf16x8*)&At[r0 + 16 + m][kk];
        #pragma unroll
        for (int ct = 0; ct < 4; ++ct) {
            int col = c0 + ct * 16 + m;
            bf16x8 b = *(const bf16x8*)(Wc16 + (size_t)col * 256 + kk);
            acc[0][ct] = __builtin_amdgcn_mfma_f32_16x16x32_bf16(a0, b, acc[0][ct], 0, 0, 0);
            acc[1][ct] = __builtin_amdgcn_mfma_f32_16x16x32_bf16(a1, b, acc[1][ct], 0, 0, 0);
        }
    }
    __syncthreads();   // done reading At

    // Phase 4: transpose-store via LDS (Ct stride 132 f32 -> 2-way only).
    float* Ct = (float*)&At[0][0];
    #pragma unroll
    for (int rt = 0; rt < 2; ++rt) {
        #pragma unroll
        for (int ct = 0; ct < 4; ++ct) {
            int ccol = c0 + ct * 16 + m;
            int crow = r0 + rt * 16 + quad * 4;
            #pragma unroll
            for (int r = 0; r < 4; ++r)
                Ct[(crow + r) * 132 + ccol] = acc[rt][ct][r];
        }
    }
    __syncthreads();
    for (int idx = tid; idx < 64 * 32; idx += 256) {
        int row = idx >> 5;
        int c4 = (idx & 31) * 4;
        int n = node0 + row;
        if (n < N_NODES) {
            float4 v = *(float4*)&Ct[row * 132 + c4];
            float4 bb = *(const float4*)(biasc + c4);
            v.x += bb.x; v.y += bb.y; v.z += bb.z; v.w += bb.w;
            *(float4*)&out[(size_t)n * D + c4] = v;
        }
    }
}

extern "C" void kernel_launch(void* const* d_in, const int* in_sizes, int n_in,
                              void* d_out, int out_size, void* d_ws, size_t ws_size,
                              hipStream_t stream) {
    const float* feat    = (const float*)d_in[0];
    const int*   src     = (const int*)d_in[1];
    const int*   dst     = (const int*)d_in[2];
    const float* W_self  = (const float*)d_in[3];
    const float* b_self  = (const float*)d_in[4];
    const float* W_neigh = (const float*)d_in[5];
    const float* bias    = (const float*)d_in[6];
    float* out = (float*)d_out;
    char*  ws  = (char*)d_ws;

    int* offsets = (int*)(ws + OFF_OFFSETS);
    int* btotal  = (int*)(ws + OFF_BTOTAL);
    int* gcursor = (int*)(ws + OFF_GCURSOR);
    int* bbase   = (int*)(ws + OFF_BBASE);
    int* csr_src = (int*)(ws + OFF_CSR);
    int* packed  = (int*)(ws + OFF_PACKED);
    __bf16* feat16 = (__bf16*)(ws + OFF_FEAT16);
    __bf16* Wc16   = (__bf16*)(ws + OFF_WC16);
    float* biasc   = (float*)(ws + OFF_BIASC);
    const int n_edges = in_sizes[1];

    hipMemsetAsync(btotal, 0, 256 * sizeof(int), stream);
    bucket_hist_kernel<<<dim3(PBLOCKS), 256, 0, stream>>>(dst, btotal, n_edges);
    bucket_scan_kernel<<<dim3(1), 64, 0, stream>>>(btotal, bbase, gcursor, offsets);
    partition_kernel<<<dim3(PBLOCKS), 256, 0, stream>>>(src, dst, gcursor, packed, n_edges);
    csr_local_kernel<<<dim3(NBUK), 256, 0, stream>>>(packed, bbase, offsets, csr_src);
    // convert_feat MUST follow csr_local: feat16 overlays packed.
    convert_feat_kernel<<<dim3((N_NODES * D / 8 + 255) / 256), 256, 0, stream>>>(feat, feat16);
    convert_w_kernel<<<dim3(33), 256, 0, stream>>>(W_self, W_neigh, b_self, bias, Wc16, biasc);
    fused_kernel<<<dim3((N_NODES + 63) / 64), 256, 0, stream>>>(feat16, offsets, csr_src,
                                                                Wc16, biasc, out);
}